// Round 2
// baseline (135.556 us; speedup 1.0000x reference)
//
#include <hip/hip_runtime.h>

// Problem constants (match reference)
#define BB 64
#define HH 480
#define WW 640
#define PP 8192
#define CHUNKS 32          // blocks per batch (PP / CHUNKS / TPB = 1 pair/thread)
#define TPB 256
#define GRID (BB * CHUNKS) // 2048 blocks -> 8 blocks/CU -> 32 waves/CU (full occupancy)

// ws layout: [0 .. GRID*4)   float partials {s_log, s_sq, n_log, n_sq} per block
//            [GRID*4]        uint counter (zeroed each launch via hipMemsetAsync)
#define WS_COUNTER_OFF (GRID * 4)

__global__ __launch_bounds__(TPB, 8) void rdl_fused(
    const float* __restrict__ depth,   // [B, H*W]
    const int*  __restrict__ xA,
    const int*  __restrict__ yA,
    const int*  __restrict__ xB,
    const int*  __restrict__ yB,
    const int*  __restrict__ rel,
    float*        __restrict__ ws,     // GRID*4 floats
    unsigned int* __restrict__ counter,
    float*        __restrict__ out)
{
    const int blk = blockIdx.x;
    const int b   = blk >> 5;          // / CHUNKS
    const int c   = blk & (CHUNKS - 1);
    const int tid = threadIdx.x;
    const int p   = b * PP + c * TPB + tid;   // one pair per thread

    // Coalesced streaming index loads (nontemporal: no reuse, keep L2 for depth)
    const int xa = __builtin_nontemporal_load(xA  + p);
    const int ya = __builtin_nontemporal_load(yA  + p);
    const int xb = __builtin_nontemporal_load(xB  + p);
    const int yb = __builtin_nontemporal_load(yB  + p);
    const int r  = __builtin_nontemporal_load(rel + p);

    const float* __restrict__ d = depth + (size_t)b * (HH * WW);
    const float zA = d[xa * WW + ya];
    const float zB = d[xb * WW + yb];
    const float pred = zA - zB;

    float s_log = 0.f, s_sq = 0.f, n_log = 0.f, n_sq = 0.f;
    if (r != 2) {
        if (r == 0) {
            s_sq = pred * pred;
            n_sq = 1.f;
        } else {
            const float x = -(float)r * pred;
            // stable softplus: max(x,0) + log1p(exp(-|x|))
            s_log = fmaxf(x, 0.f) + log1pf(expf(-fabsf(x)));
            n_log = 1.f;
        }
    }

    // 64-lane wave reduction
#pragma unroll
    for (int off = 32; off > 0; off >>= 1) {
        s_log += __shfl_down(s_log, off);
        s_sq  += __shfl_down(s_sq,  off);
        n_log += __shfl_down(n_log, off);
        n_sq  += __shfl_down(n_sq,  off);
    }

    __shared__ float4 lds[TPB / 64];
    const int wave = tid >> 6;
    if ((tid & 63) == 0)
        lds[wave] = make_float4(s_log, s_sq, n_log, n_sq);
    __syncthreads();

    __shared__ int isLast;
    if (tid == 0) {
        float4 acc = lds[0];
#pragma unroll
        for (int wv = 1; wv < TPB / 64; ++wv) {
            acc.x += lds[wv].x;
            acc.y += lds[wv].y;
            acc.z += lds[wv].z;
            acc.w += lds[wv].w;
        }
        // device-scope publication of this block's partial
        __hip_atomic_store(&ws[blk * 4 + 0], acc.x, __ATOMIC_RELAXED, __HIP_MEMORY_SCOPE_AGENT);
        __hip_atomic_store(&ws[blk * 4 + 1], acc.y, __ATOMIC_RELAXED, __HIP_MEMORY_SCOPE_AGENT);
        __hip_atomic_store(&ws[blk * 4 + 2], acc.z, __ATOMIC_RELAXED, __HIP_MEMORY_SCOPE_AGENT);
        __hip_atomic_store(&ws[blk * 4 + 3], acc.w, __ATOMIC_RELAXED, __HIP_MEMORY_SCOPE_AGENT);
        __threadfence();
        const unsigned int old =
            __hip_atomic_fetch_add(counter, 1u, __ATOMIC_ACQ_REL, __HIP_MEMORY_SCOPE_AGENT);
        isLast = (old == GRID - 1);
    }
    __syncthreads();
    if (!isLast) return;

    // ---- last block: final reduction across all GRID partials ----
    __threadfence();
    // 4 threads per batch; thread (batch, sub) reads chunks [sub*8, sub*8+8)
    const int batch = tid >> 2;        // 0..63
    const int sub   = tid & 3;
    float sl = 0.f, ss = 0.f, nl = 0.f, ns = 0.f;
#pragma unroll
    for (int k = 0; k < CHUNKS / 4; ++k) {
        const int chunk = sub * (CHUNKS / 4) + k;
        const int base  = (batch * CHUNKS + chunk) * 4;
        sl += __hip_atomic_load(&ws[base + 0], __ATOMIC_RELAXED, __HIP_MEMORY_SCOPE_AGENT);
        ss += __hip_atomic_load(&ws[base + 1], __ATOMIC_RELAXED, __HIP_MEMORY_SCOPE_AGENT);
        nl += __hip_atomic_load(&ws[base + 2], __ATOMIC_RELAXED, __HIP_MEMORY_SCOPE_AGENT);
        ns += __hip_atomic_load(&ws[base + 3], __ATOMIC_RELAXED, __HIP_MEMORY_SCOPE_AGENT);
    }
    // combine the 4 sub-threads of each batch (contiguous lanes -> same wave)
#pragma unroll
    for (int off = 1; off < 4; off <<= 1) {
        sl += __shfl_xor(sl, off);
        ss += __shfl_xor(ss, off);
        nl += __shfl_xor(nl, off);
        ns += __shfl_xor(ns, off);
    }
    __shared__ float lossArr[BB];
    if (sub == 0)
        lossArr[batch] = sl / nl + ss / ns;   // per-batch log_loss + sq_loss
    __syncthreads();
    if (tid < BB) {
        float loss = lossArr[tid];
#pragma unroll
        for (int off = 32; off > 0; off >>= 1)
            loss += __shfl_down(loss, off);
        if (tid == 0)
            out[0] = loss * (1.0f / (float)BB);
    }
}

extern "C" void kernel_launch(void* const* d_in, const int* in_sizes, int n_in,
                              void* d_out, int out_size, void* d_ws, size_t ws_size,
                              hipStream_t stream) {
    const float* depth = (const float*)d_in[0];
    const int*   xA    = (const int*)d_in[1];
    const int*   yA    = (const int*)d_in[2];
    const int*   xB    = (const int*)d_in[3];
    const int*   yB    = (const int*)d_in[4];
    const int*   rel   = (const int*)d_in[5];
    float*       out   = (float*)d_out;
    float*       ws    = (float*)d_ws;                      // GRID*4 floats + counter
    unsigned int* counter = (unsigned int*)(ws + WS_COUNTER_OFF);

    // zero the arrival counter every launch (capturable memset node)
    hipMemsetAsync(counter, 0, sizeof(unsigned int), stream);

    rdl_fused<<<GRID, TPB, 0, stream>>>(depth, xA, yA, xB, yB, rel, ws, counter, out);
}

// Round 3
// 26.442 us; speedup vs baseline: 5.1266x; 5.1266x over previous
//
#include <hip/hip_runtime.h>

// Problem constants (match reference)
#define BB 64
#define HH 480
#define WW 640
#define PP 8192
#define CHUNKS 16          // blocks per batch; PP/CHUNKS = 512 = TPB*2 -> 2 pairs/thread
#define TPB 256
#define GRID (BB * CHUNKS) // 1024 blocks -> 4 blocks/CU -> 16 waves/CU

__global__ __launch_bounds__(TPB) void rdl_partial(
    const float* __restrict__ depth,   // [B, H*W]
    const int*  __restrict__ xA,
    const int*  __restrict__ yA,
    const int*  __restrict__ xB,
    const int*  __restrict__ yB,
    const int*  __restrict__ rel,
    float4*     __restrict__ ws)       // [GRID] partials {s_log, s_sq, n_log, n_sq}
{
    const int blk = blockIdx.x;
    const int b   = blk >> 4;          // / CHUNKS
    const int c   = blk & (CHUNKS - 1);
    const int tid = threadIdx.x;
    const int pair0 = b * PP + c * (PP / CHUNKS) + tid * 2;

    // Coalesced vector index loads (plain: L2-cached, cheap)
    const int2 xa2 = *reinterpret_cast<const int2*>(xA  + pair0);
    const int2 ya2 = *reinterpret_cast<const int2*>(yA  + pair0);
    const int2 xb2 = *reinterpret_cast<const int2*>(xB  + pair0);
    const int2 yb2 = *reinterpret_cast<const int2*>(yB  + pair0);
    const int2 rr2 = *reinterpret_cast<const int2*>(rel + pair0);

    const int xas[2] = {xa2.x, xa2.y};
    const int yas[2] = {ya2.x, ya2.y};
    const int xbs[2] = {xb2.x, xb2.y};
    const int ybs[2] = {yb2.x, yb2.y};
    const int rs [2] = {rr2.x, rr2.y};

    const float* __restrict__ d = depth + (size_t)b * (HH * WW);

    // Issue all 4 gathers up front (independent -> 4 outstanding VMEM ops)
    float zA[2], zB[2];
#pragma unroll
    for (int k = 0; k < 2; ++k) {
        zA[k] = d[xas[k] * WW + yas[k]];
        zB[k] = d[xbs[k] * WW + ybs[k]];
    }

    float s_log = 0.f, s_sq = 0.f;
    int   n_log = 0,   n_sq = 0;
#pragma unroll
    for (int k = 0; k < 2; ++k) {
        const float pred = zA[k] - zB[k];
        const int r = rs[k];
        if (r != 2) {
            if (r == 0) {
                s_sq += pred * pred;
                n_sq++;
            } else {
                const float x = -(float)r * pred;
                // stable softplus: max(x,0) + log1p(exp(-|x|))
                s_log += fmaxf(x, 0.f) + log1pf(expf(-fabsf(x)));
                n_log++;
            }
        }
    }

    // 64-lane wave reduction
#pragma unroll
    for (int off = 32; off > 0; off >>= 1) {
        s_log += __shfl_down(s_log, off);
        s_sq  += __shfl_down(s_sq,  off);
        n_log += __shfl_down(n_log, off);
        n_sq  += __shfl_down(n_sq,  off);
    }

    __shared__ float4 lds[TPB / 64];
    const int wave = tid >> 6;
    if ((tid & 63) == 0)
        lds[wave] = make_float4(s_log, s_sq, (float)n_log, (float)n_sq);
    __syncthreads();

    if (tid == 0) {
        float4 acc = lds[0];
#pragma unroll
        for (int wv = 1; wv < TPB / 64; ++wv) {
            acc.x += lds[wv].x;
            acc.y += lds[wv].y;
            acc.z += lds[wv].z;
            acc.w += lds[wv].w;
        }
        ws[blk] = acc;
    }
}

__global__ __launch_bounds__(TPB) void rdl_final(
    const float4* __restrict__ ws,     // [BB*CHUNKS] = 1024 partials
    float*        __restrict__ out)
{
    const int tid   = threadIdx.x;     // 256 threads
    const int batch = tid >> 2;        // 0..63
    const int sub   = tid & 3;         // 4 threads per batch
    float sl = 0.f, ss = 0.f, nl = 0.f, ns = 0.f;
#pragma unroll
    for (int k = 0; k < CHUNKS / 4; ++k) {
        const float4 v = ws[batch * CHUNKS + sub * (CHUNKS / 4) + k];
        sl += v.x; ss += v.y; nl += v.z; ns += v.w;
    }
    // combine the 4 sub-threads of each batch (contiguous lanes, same wave)
#pragma unroll
    for (int off = 1; off < 4; off <<= 1) {
        sl += __shfl_xor(sl, off);
        ss += __shfl_xor(ss, off);
        nl += __shfl_xor(nl, off);
        ns += __shfl_xor(ns, off);
    }
    __shared__ float lossArr[BB];
    if (sub == 0)
        lossArr[batch] = sl / nl + ss / ns;   // per-batch log_loss + sq_loss
    __syncthreads();
    if (tid < BB) {                    // wave 0
        float loss = lossArr[tid];
#pragma unroll
        for (int off = 32; off > 0; off >>= 1)
            loss += __shfl_down(loss, off);
        if (tid == 0)
            out[0] = loss * (1.0f / (float)BB);
    }
}

extern "C" void kernel_launch(void* const* d_in, const int* in_sizes, int n_in,
                              void* d_out, int out_size, void* d_ws, size_t ws_size,
                              hipStream_t stream) {
    const float* depth = (const float*)d_in[0];
    const int*   xA    = (const int*)d_in[1];
    const int*   yA    = (const int*)d_in[2];
    const int*   xB    = (const int*)d_in[3];
    const int*   yB    = (const int*)d_in[4];
    const int*   rel   = (const int*)d_in[5];
    float*       out   = (float*)d_out;
    float4*      ws    = (float4*)d_ws;   // GRID*16 B = 16 KiB

    rdl_partial<<<GRID, TPB, 0, stream>>>(depth, xA, yA, xB, yB, rel, ws);
    rdl_final<<<1, TPB, 0, stream>>>(ws, out);
}